// Round 12
// baseline (120.022 us; speedup 1.0000x reference)
//
#include <hip/hip_runtime.h>

typedef __attribute__((ext_vector_type(8))) short short8;
typedef __attribute__((ext_vector_type(8))) _Float16 half8;
typedef __attribute__((ext_vector_type(4))) float floatx4;
typedef __attribute__((ext_vector_type(4))) float floatv4;
typedef __attribute__((ext_vector_type(4))) short short4v;
typedef __attribute__((ext_vector_type(4))) unsigned short ushort4v;
typedef unsigned short u16;

#define MFMA_BF16(a,b,c) __builtin_amdgcn_mfma_f32_16x16x32_bf16((a),(b),(c),0,0,0)
#define MFMA_F16(a,b,c)  __builtin_amdgcn_mfma_f32_16x16x32_f16((a),(b),(c),0,0,0)

__device__ __forceinline__ u16 f2bf(float f) {
    union { float f; unsigned u; } v; v.f = f;
    unsigned r = (v.u + 0x7fffu + ((v.u >> 16) & 1u)) >> 16;
    return (u16)r;
}
__device__ __forceinline__ float bf2f(u16 h) {
    union { unsigned u; float f; } v; v.u = ((unsigned)h) << 16;
    return v.f;
}
__device__ __forceinline__ u16 f2h(float f) {
    union { _Float16 h; u16 u; } v; v.h = (_Float16)f;
    return v.u;
}

__device__ __forceinline__ void gll16(const u16* g, u16* l) {
    __builtin_amdgcn_global_load_lds(
        (const __attribute__((address_space(1))) void*)g,
        (__attribute__((address_space(3))) void*)l, 16, 0, 0);
}

// ---------------------------------------------------------------------------
// prep_kernel: sniff + x -> xT f16 (transpose) + W -> f16 stacked Wall[1536][512]
// (Wq rows 0-511, Wk 512-1023, Wv 1024-1535) + Wo16. Vectorized 4x.
// ---------------------------------------------------------------------------
__global__ __launch_bounds__(256) void prep_kernel(
    const void* __restrict__ x,
    const void* __restrict__ Wq, const void* __restrict__ Wk,
    const void* __restrict__ Wv, const void* __restrict__ Wo,
    u16* __restrict__ xT, u16* __restrict__ Wall, u16* __restrict__ Wo16,
    int* __restrict__ flag)
{
    __shared__ float tile[64][65];
    __shared__ int sflag;
    const int tid = threadIdx.x;

    if (tid < 64) {
        u16 u = ((const u16*)x)[2 * tid];
        int e = (u >> 7) & 0xFF;
        unsigned long long m = __ballot(e >= 96 && e <= 140);
        if (tid == 0) sflag = (__popcll(m) >= 40) ? 0 : 1;
    }
    __syncthreads();
    const int isf32 = sflag;
    const int bid = blockIdx.x;
    if (bid == 0 && tid == 0) *flag = isf32;

    if (bid < 512) {
        const int b = bid >> 7, rem = bid & 127;
        const int c0 = (rem >> 4) * 64, n0 = (rem & 15) * 64;
        const int cr = tid >> 4;          // 0..15
        const int n4 = (tid & 15) * 4;
        const size_t base = (size_t)b * 512 * 1024;
        #pragma unroll
        for (int i = 0; i < 4; ++i) {
            int c = i * 16 + cr;
            size_t idx = base + (size_t)(c0 + c) * 1024 + n0 + n4;
            float v0, v1, v2, v3;
            if (isf32) {
                floatv4 v = *(const floatv4*)((const float*)x + idx);
                v0 = v[0]; v1 = v[1]; v2 = v[2]; v3 = v[3];
            } else {
                ushort4v u = *(const ushort4v*)((const u16*)x + idx);
                v0 = bf2f(u[0]); v1 = bf2f(u[1]); v2 = bf2f(u[2]); v3 = bf2f(u[3]);
            }
            tile[c][n4 + 0] = v0; tile[c][n4 + 1] = v1;
            tile[c][n4 + 2] = v2; tile[c][n4 + 3] = v3;
        }
        __syncthreads();
        const int nr = tid >> 4;
        const int c4 = (tid & 15) * 4;
        #pragma unroll
        for (int i = 0; i < 4; ++i) {
            int n = i * 16 + nr;
            short4v o;
            o[0] = (short)f2h(tile[c4 + 0][n]);
            o[1] = (short)f2h(tile[c4 + 1][n]);
            o[2] = (short)f2h(tile[c4 + 2][n]);
            o[3] = (short)f2h(tile[c4 + 3][n]);
            *(short4v*)(xT + ((size_t)b * 1024 + n0 + n) * 512 + c0 + c4) = o;
        }
    } else {
        const int b2 = bid - 512;   // 0..63
        #pragma unroll
        for (int m = 0; m < 4; ++m) {
            const void* src = (m == 0) ? Wq : (m == 1) ? Wk : (m == 2) ? Wv : Wo;
            u16* dst = (m == 3) ? Wo16 : (Wall + m * 262144);
            #pragma unroll
            for (int j = 0; j < 4; ++j) {
                int i = b2 * 4096 + j * 1024 + tid * 4;
                short4v o;
                if (isf32) {
                    floatv4 v = *(const floatv4*)((const float*)src + i);
                    o[0] = (short)f2h(v[0]); o[1] = (short)f2h(v[1]);
                    o[2] = (short)f2h(v[2]); o[3] = (short)f2h(v[3]);
                } else {
                    ushort4v u = *(const ushort4v*)((const u16*)src + i);
                    o[0] = (short)f2h(bf2f(u[0])); o[1] = (short)f2h(bf2f(u[1]));
                    o[2] = (short)f2h(bf2f(u[2])); o[3] = (short)f2h(bf2f(u[3]));
                }
                *(short4v*)(dst + i) = o;
            }
        }
    }
}

// ---------------------------------------------------------------------------
// gemm_2t: 128(M) x 128(N) f16 GEMM core, K=512, BK=32, double-buffered,
// one barrier/step, swizzled LDS. Chunks/buffer: A 0-7, B 8-15 (16 KB).
// 4 waves, wave tile 64x64 -> acc[4][4].
// ---------------------------------------------------------------------------
__device__ __forceinline__ void stage_2t(
    const u16* __restrict__ A, const u16* __restrict__ B,
    u16* L, int k0, int wave, int srow, int koff)
{
    #pragma unroll
    for (int i = 0; i < 4; ++i) {
        int idx = wave + i * 4;
        const u16* s;
        if (idx < 8) s = A + (idx * 16 + srow) * 512 + k0 + koff;
        else         s = B + ((idx - 8) * 16 + srow) * 512 + k0 + koff;
        gll16(s, L + idx * 512);
    }
}

__device__ __forceinline__ void gemm_2t(
    const u16* __restrict__ A, const u16* __restrict__ B,
    u16* lds, floatx4 acc[4][4], int lane, int wave)
{
    const int quad = lane >> 4, l16 = lane & 15;
    const int msub = (wave & 1) * 64, nsub = (wave >> 1) * 64;
    const int srow = lane >> 2;
    const int koff = (((lane & 3) - (srow >> 1)) & 3) * 8;
    const int pA = ((quad + (l16 >> 1)) & 3) * 8;

    stage_2t(A, B, lds, 0, wave, srow, koff);
    for (int k0 = 0; k0 < 512; k0 += 32) {
        __syncthreads();
        u16* L = lds + ((k0 >> 5) & 1) * 8192;
        if (k0 + 32 < 512)
            stage_2t(A, B, lds + (((k0 >> 5) + 1) & 1) * 8192,
                     k0 + 32, wave, srow, koff);

        half8 ah[4], bh[4];
        #pragma unroll
        for (int mt = 0; mt < 4; ++mt)
            ah[mt] = *(const half8*)(L + (msub + mt * 16 + l16) * 32 + pA);
        #pragma unroll
        for (int nt = 0; nt < 4; ++nt)
            bh[nt] = *(const half8*)(L + 4096 + (nsub + nt * 16 + l16) * 32 + pA);
        #pragma unroll
        for (int mt = 0; mt < 4; ++mt)
            #pragma unroll
            for (int nt = 0; nt < 4; ++nt)
                acc[mt][nt] = MFMA_F16(ah[mt], bh[nt], acc[mt][nt]);
    }
}

// ---------------------------------------------------------------------------
// proj_kernel: unified q/k/v. Grid (32 m-tiles, 12 o-tiles) = 384 blocks.
// A = xT rows (stacked b,n), B = Wall rows (o in 0..1535).
// Epilogue: o<512 -> qT; o<1024 -> kT; else vbuf.
// ---------------------------------------------------------------------------
__global__ __launch_bounds__(256) void proj_kernel(
    const u16* __restrict__ xT, const u16* __restrict__ Wall,
    u16* __restrict__ qT, u16* __restrict__ kT,
    u16* __restrict__ vbuf)
{
    __shared__ u16 lds[16384];   // 32 KB
    const int lane = threadIdx.x & 63;
    const int wave = threadIdx.x >> 6;
    const int quad = lane >> 4, l16 = lane & 15;
    const int m0 = blockIdx.x * 128;       // stacked (b,n)
    const int oblk = blockIdx.y * 128;     // o in 0..1535
    const int msub = (wave & 1) * 64, nsub = (wave >> 1) * 64;

    floatx4 acc[4][4];
    #pragma unroll
    for (int i = 0; i < 4; ++i)
        #pragma unroll
        for (int j = 0; j < 4; ++j) acc[i][j] = (floatx4){0.f, 0.f, 0.f, 0.f};

    gemm_2t(xT + (size_t)m0 * 512, Wall + (size_t)oblk * 512, lds, acc, lane, wave);

    if (oblk < 1024) {
        u16* dst = (oblk < 512) ? qT : kT;
        const int obase = oblk & 511;
        #pragma unroll
        for (int mt = 0; mt < 4; ++mt)
            #pragma unroll
            for (int r = 0; r < 4; ++r) {
                int row = m0 + msub + mt * 16 + quad * 4 + r;
                int b = row >> 10, n = row & 1023;
                #pragma unroll
                for (int nt = 0; nt < 4; ++nt) {
                    int o = obase + nsub + nt * 16 + l16;
                    int head = b * 8 + (o >> 6);
                    int dd = o & 63;
                    dst[(head * 1024 + n) * 64 + dd] = f2h(acc[mt][nt][r]);
                }
            }
    } else {
        const int obase = oblk - 1024;
        #pragma unroll
        for (int mt = 0; mt < 4; ++mt)
            #pragma unroll
            for (int r = 0; r < 4; ++r) {
                int row = m0 + msub + mt * 16 + quad * 4 + r;
                int b = row >> 10, n = row & 1023;
                #pragma unroll
                for (int nt = 0; nt < 4; ++nt) {
                    int o = obase + nsub + nt * 16 + l16;
                    vbuf[b * 524288 + o * 1024 + n] = f2bf(acc[mt][nt][r]);
                }
            }
    }
}

// ---------------------------------------------------------------------------
// attn_kernel: 512 threads (8 waves = 128 queries), grid (head=32, qtile=8).
// S^T formulation: S^T = K.Q^T; P^T B-frags via register shuffles;
// O^T = V^T.P^T. K(f16)/V(bf16) double-buffered; LDS 32 KB.
// ---------------------------------------------------------------------------
__global__ __launch_bounds__(512) void attn_kernel(
    const u16* __restrict__ qT, const u16* __restrict__ kT,
    const u16* __restrict__ vbuf,
    u16* __restrict__ yT)
{
    __shared__ u16 lds[16384];   // 2 x 8192 shorts
    const int lane = threadIdx.x & 63;
    const int wave = threadIdx.x >> 6;      // 0..7
    const int quad = lane >> 4, l16 = lane & 15;
    const int head = blockIdx.x;
    const int i0 = blockIdx.y * 128 + wave * 16;
    const int b = head >> 3, h = head & 7;
    const u16* qp = qT + head * 65536;
    const u16* kp = kT + head * 65536;
    const u16* vb = vbuf + b * 524288 + h * 65536;
    const int srow = lane >> 2;
    const int koff = (((lane & 3) - (srow >> 1)) & 3) * 8;
    const int pA = ((quad + (l16 >> 1)) & 3) * 8;

    const int qoff = (i0 + l16) * 64 + quad * 8;
    half8 aq0 = *(const half8*)(qp + qoff);
    half8 aq1 = *(const half8*)(qp + qoff + 32);

    float lsum = 0.f;
    floatx4 oacc[4];
    #pragma unroll
    for (int dt = 0; dt < 4; ++dt) oacc[dt] = (floatx4){0.f, 0.f, 0.f, 0.f};

    const float L2E = 1.44269504f;
    const float C2  = 69.2493619f;   // 48 * log2(e)

    auto stage_kv = [&](int j0, u16* L) {
        #pragma unroll
        for (int i = 0; i < 2; ++i) {
            int c = wave + i * 8;
            const u16* s;
            if (c < 8) {
                int kc = c >> 2, r0 = (c & 3) * 16;
                s = kp + (j0 + r0 + srow) * 64 + kc * 32 + koff;
            } else {
                int c8 = c - 8, js = c8 >> 2, r0 = (c8 & 3) * 16;
                s = vb + (r0 + srow) * 1024 + j0 + js * 32 + koff;
            }
            gll16(s, L + c * 512);
        }
    };

    stage_kv(0, lds);

    const int srcA = (quad & 1) * 32 + l16;
    const int srcB = srcA + 16;
    const bool hi = (quad >> 1) != 0;

    for (int j0 = 0; j0 < 1024; j0 += 64) {
        __syncthreads();
        u16* L = lds + ((j0 >> 6) & 1) * 8192;
        if (j0 + 64 < 1024)
            stage_kv(j0 + 64, lds + (((j0 >> 6) + 1) & 1) * 8192);

        unsigned pk[4][2];
        #pragma unroll
        for (int jt = 0; jt < 4; ++jt) {
            int off = jt * 512 + l16 * 32 + pA;
            half8 kh0 = *(const half8*)(L + off);
            half8 kh1 = *(const half8*)(L + 2048 + off);
            floatx4 s = {0.f, 0.f, 0.f, 0.f};
            s = MFMA_F16(kh0, aq0, s);
            s = MFMA_F16(kh1, aq1, s);
            float p0 = __builtin_amdgcn_exp2f(s[0] * L2E - C2);
            float p1 = __builtin_amdgcn_exp2f(s[1] * L2E - C2);
            float p2 = __builtin_amdgcn_exp2f(s[2] * L2E - C2);
            float p3 = __builtin_amdgcn_exp2f(s[3] * L2E - C2);
            lsum += (p0 + p1) + (p2 + p3);
            pk[jt][0] = (unsigned)f2bf(p0) | ((unsigned)f2bf(p1) << 16);
            pk[jt][1] = (unsigned)f2bf(p2) | ((unsigned)f2bf(p3) << 16);
        }

        #pragma unroll
        for (int jc = 0; jc < 2; ++jc) {
            unsigned a0 = (unsigned)__shfl((int)pk[jc * 2][0], srcA);
            unsigned b0 = (unsigned)__shfl((int)pk[jc * 2 + 1][0], srcA);
            unsigned a1 = (unsigned)__shfl((int)pk[jc * 2][1], srcA);
            unsigned b1 = (unsigned)__shfl((int)pk[jc * 2 + 1][1], srcA);
            unsigned a2 = (unsigned)__shfl((int)pk[jc * 2][0], srcB);
            unsigned b2 = (unsigned)__shfl((int)pk[jc * 2 + 1][0], srcB);
            unsigned a3 = (unsigned)__shfl((int)pk[jc * 2][1], srcB);
            unsigned b3 = (unsigned)__shfl((int)pk[jc * 2 + 1][1], srcB);
            union { unsigned u[4]; short8 s8; } pu;
            pu.u[0] = hi ? b0 : a0;
            pu.u[1] = hi ? b1 : a1;
            pu.u[2] = hi ? b2 : a2;
            pu.u[3] = hi ? b3 : a3;
            short8 pfrag = pu.s8;
            #pragma unroll
            for (int dt = 0; dt < 4; ++dt) {
                int off = dt * 512 + l16 * 32 + pA;
                short8 vv = *(const short8*)(L + 4096 + jc * 2048 + off);
                oacc[dt] = MFMA_BF16(vv, pfrag, oacc[dt]);
            }
        }
    }

    lsum += __shfl_xor(lsum, 16);
    lsum += __shfl_xor(lsum, 32);
    const float linv = 1.0f / lsum;

    u16* yrow = yT + ((size_t)b * 1024 + i0 + l16) * 512 + h * 64;
    #pragma unroll
    for (int dt = 0; dt < 4; ++dt) {
        short4v o;
        #pragma unroll
        for (int r = 0; r < 4; ++r) o[r] = (short)f2h(oacc[dt][r] * linv);
        *(short4v*)(yrow + dt * 16 + quad * 4) = o;
    }
}

// ---------------------------------------------------------------------------
// out_kernel: Wo(f16) @ yT(f16), 128x128 tiles, grid (32 ntiles, 4 otiles)
// = 128 blocks.
// ---------------------------------------------------------------------------
__global__ __launch_bounds__(256) void out_kernel(
    const u16* __restrict__ Woh, const u16* __restrict__ yT,
    void* __restrict__ out, const int* __restrict__ flag)
{
    __shared__ u16 lds[16384];
    const int isf32 = *flag;
    const int lane = threadIdx.x & 63;
    const int wave = threadIdx.x >> 6;
    const int quad = lane >> 4, l16 = lane & 15;
    const int nblk = blockIdx.x * 128;   // stacked (b,n)
    const int oblk = blockIdx.y * 128;   // o

    floatx4 acc[4][4];
    #pragma unroll
    for (int i = 0; i < 4; ++i)
        #pragma unroll
        for (int j = 0; j < 4; ++j) acc[i][j] = (floatx4){0.f, 0.f, 0.f, 0.f};

    gemm_2t(Woh + (size_t)oblk * 512, yT + (size_t)nblk * 512, lds, acc, lane, wave);

    const int msub = (wave & 1) * 64, nsub = (wave >> 1) * 64;
    #pragma unroll
    for (int mt = 0; mt < 4; ++mt)
        #pragma unroll
        for (int r = 0; r < 4; ++r) {
            int o = oblk + msub + mt * 16 + quad * 4 + r;
            #pragma unroll
            for (int nt = 0; nt < 4; ++nt) {
                int col = nblk + nsub + nt * 16 + l16;
                int b = col >> 10, n = col & 1023;
                size_t di = (size_t)b * 524288 + o * 1024 + n;
                if (isf32) ((float*)out)[di] = acc[mt][nt][r];
                else       ((u16*)out)[di] = f2bf(acc[mt][nt][r]);
            }
        }
}

extern "C" void kernel_launch(void* const* d_in, const int* in_sizes, int n_in,
                              void* d_out, int out_size, void* d_ws, size_t ws_size,
                              hipStream_t stream)
{
    const void* x  = d_in[0];
    const void* Wq = d_in[1];
    const void* Wk = d_in[2];
    const void* Wv = d_in[3];
    const void* Wo = d_in[4];

    const int NX = 4 * 512 * 1024;
    const int NW = 512 * 512;

    char* p = (char*)d_ws;
    int* flag = (int*)p; p += 64;
    u16* xT   = (u16*)p; p += (size_t)NX * 2;
    u16* Wall = (u16*)p; p += (size_t)NW * 3 * 2;
    u16* Woh  = (u16*)p; p += (size_t)NW * 2;
    u16* qT   = (u16*)p; p += (size_t)NX * 2;
    u16* kT   = (u16*)p; p += (size_t)NX * 2;
    u16* vbuf = (u16*)p; p += (size_t)NX * 2;
    u16* ybuf = (u16*)p; p += (size_t)NX * 2;

    prep_kernel<<<576, 256, 0, stream>>>(
        x, Wq, Wk, Wv, Wo, xT, Wall, Woh, flag);
    proj_kernel<<<dim3(32, 12), 256, 0, stream>>>(
        xT, Wall, qT, kT, vbuf);
    attn_kernel<<<dim3(32, 8), 512, 0, stream>>>(
        qT, kT, vbuf, ybuf);
    out_kernel<<<dim3(32, 4), 256, 0, stream>>>(
        Woh, ybuf, d_out, flag);
}

// Round 13
// 117.749 us; speedup vs baseline: 1.0193x; 1.0193x over previous
//
#include <hip/hip_runtime.h>

typedef __attribute__((ext_vector_type(8))) short short8;
typedef __attribute__((ext_vector_type(8))) _Float16 half8;
typedef __attribute__((ext_vector_type(4))) float floatx4;
typedef __attribute__((ext_vector_type(4))) float floatv4;
typedef __attribute__((ext_vector_type(4))) short short4v;
typedef __attribute__((ext_vector_type(4))) unsigned short ushort4v;
typedef unsigned short u16;

#define MFMA_BF16(a,b,c) __builtin_amdgcn_mfma_f32_16x16x32_bf16((a),(b),(c),0,0,0)
#define MFMA_F16(a,b,c)  __builtin_amdgcn_mfma_f32_16x16x32_f16((a),(b),(c),0,0,0)

__device__ __forceinline__ u16 f2bf(float f) {
    union { float f; unsigned u; } v; v.f = f;
    unsigned r = (v.u + 0x7fffu + ((v.u >> 16) & 1u)) >> 16;
    return (u16)r;
}
__device__ __forceinline__ float bf2f(u16 h) {
    union { unsigned u; float f; } v; v.u = ((unsigned)h) << 16;
    return v.f;
}
__device__ __forceinline__ u16 f2h(float f) {
    union { _Float16 h; u16 u; } v; v.h = (_Float16)f;
    return v.u;
}

__device__ __forceinline__ void gll16(const u16* g, u16* l) {
    __builtin_amdgcn_global_load_lds(
        (const __attribute__((address_space(1))) void*)g,
        (__attribute__((address_space(3))) void*)l, 16, 0, 0);
}

// ---------------------------------------------------------------------------
// prep_kernel: sniff + x -> xT f16 (transpose) + W -> f16 stacked Wall[1536][512]
// (Wq 0-511, Wk 512-1023, Wv 1024-1535) + Wo16. Vectorized 4x.
// ---------------------------------------------------------------------------
__global__ __launch_bounds__(256) void prep_kernel(
    const void* __restrict__ x,
    const void* __restrict__ Wq, const void* __restrict__ Wk,
    const void* __restrict__ Wv, const void* __restrict__ Wo,
    u16* __restrict__ xT, u16* __restrict__ Wall, u16* __restrict__ Wo16,
    int* __restrict__ flag)
{
    __shared__ float tile[64][65];
    __shared__ int sflag;
    const int tid = threadIdx.x;

    if (tid < 64) {
        u16 u = ((const u16*)x)[2 * tid];
        int e = (u >> 7) & 0xFF;
        unsigned long long m = __ballot(e >= 96 && e <= 140);
        if (tid == 0) sflag = (__popcll(m) >= 40) ? 0 : 1;
    }
    __syncthreads();
    const int isf32 = sflag;
    const int bid = blockIdx.x;
    if (bid == 0 && tid == 0) *flag = isf32;

    if (bid < 512) {
        const int b = bid >> 7, rem = bid & 127;
        const int c0 = (rem >> 4) * 64, n0 = (rem & 15) * 64;
        const int cr = tid >> 4;
        const int n4 = (tid & 15) * 4;
        const size_t base = (size_t)b * 512 * 1024;
        #pragma unroll
        for (int i = 0; i < 4; ++i) {
            int c = i * 16 + cr;
            size_t idx = base + (size_t)(c0 + c) * 1024 + n0 + n4;
            float v0, v1, v2, v3;
            if (isf32) {
                floatv4 v = *(const floatv4*)((const float*)x + idx);
                v0 = v[0]; v1 = v[1]; v2 = v[2]; v3 = v[3];
            } else {
                ushort4v u = *(const ushort4v*)((const u16*)x + idx);
                v0 = bf2f(u[0]); v1 = bf2f(u[1]); v2 = bf2f(u[2]); v3 = bf2f(u[3]);
            }
            tile[c][n4 + 0] = v0; tile[c][n4 + 1] = v1;
            tile[c][n4 + 2] = v2; tile[c][n4 + 3] = v3;
        }
        __syncthreads();
        const int nr = tid >> 4;
        const int c4 = (tid & 15) * 4;
        #pragma unroll
        for (int i = 0; i < 4; ++i) {
            int n = i * 16 + nr;
            short4v o;
            o[0] = (short)f2h(tile[c4 + 0][n]);
            o[1] = (short)f2h(tile[c4 + 1][n]);
            o[2] = (short)f2h(tile[c4 + 2][n]);
            o[3] = (short)f2h(tile[c4 + 3][n]);
            *(short4v*)(xT + ((size_t)b * 1024 + n0 + n) * 512 + c0 + c4) = o;
        }
    } else {
        const int b2 = bid - 512;   // 0..63
        #pragma unroll
        for (int m = 0; m < 4; ++m) {
            const void* src = (m == 0) ? Wq : (m == 1) ? Wk : (m == 2) ? Wv : Wo;
            u16* dst = (m == 3) ? Wo16 : (Wall + m * 262144);
            #pragma unroll
            for (int j = 0; j < 4; ++j) {
                int i = b2 * 4096 + j * 1024 + tid * 4;
                short4v o;
                if (isf32) {
                    floatv4 v = *(const floatv4*)((const float*)src + i);
                    o[0] = (short)f2h(v[0]); o[1] = (short)f2h(v[1]);
                    o[2] = (short)f2h(v[2]); o[3] = (short)f2h(v[3]);
                } else {
                    ushort4v u = *(const ushort4v*)((const u16*)src + i);
                    o[0] = (short)f2h(bf2f(u[0])); o[1] = (short)f2h(bf2f(u[1]));
                    o[2] = (short)f2h(bf2f(u[2])); o[3] = (short)f2h(bf2f(u[3]));
                }
                *(short4v*)(dst + i) = o;
            }
        }
    }
}

// ---------------------------------------------------------------------------
// gemm_1t: 64(M) x 128(N) f16 GEMM core, K=512, BK=32, double-buffered,
// one barrier/step, swizzled LDS. Chunks/buffer: A 0-3, B 4-11 (12 KB).
// 4 waves, wave tile 32m x 64n -> acc[2][4].
// ---------------------------------------------------------------------------
__device__ __forceinline__ void stage_1t(
    const u16* __restrict__ A, const u16* __restrict__ B,
    u16* L, int k0, int wave, int srow, int koff)
{
    #pragma unroll
    for (int i = 0; i < 3; ++i) {
        int idx = wave + i * 4;
        const u16* s;
        if (idx < 4) s = A + (idx * 16 + srow) * 512 + k0 + koff;
        else         s = B + ((idx - 4) * 16 + srow) * 512 + k0 + koff;
        gll16(s, L + idx * 512);
    }
}

__device__ __forceinline__ void gemm_1t(
    const u16* __restrict__ A, const u16* __restrict__ B,
    u16* lds, floatx4 acc[2][4], int lane, int wave)
{
    const int quad = lane >> 4, l16 = lane & 15;
    const int msub = (wave & 1) * 32, nsub = (wave >> 1) * 64;
    const int srow = lane >> 2;
    const int koff = (((lane & 3) - (srow >> 1)) & 3) * 8;
    const int pA = ((quad + (l16 >> 1)) & 3) * 8;

    stage_1t(A, B, lds, 0, wave, srow, koff);
    for (int k0 = 0; k0 < 512; k0 += 32) {
        __syncthreads();
        u16* L = lds + ((k0 >> 5) & 1) * 6144;
        if (k0 + 32 < 512)
            stage_1t(A, B, lds + (((k0 >> 5) + 1) & 1) * 6144,
                     k0 + 32, wave, srow, koff);

        half8 ah[2], bh[4];
        #pragma unroll
        for (int mt = 0; mt < 2; ++mt)
            ah[mt] = *(const half8*)(L + (msub + mt * 16 + l16) * 32 + pA);
        #pragma unroll
        for (int nt = 0; nt < 4; ++nt)
            bh[nt] = *(const half8*)(L + 2048 + (nsub + nt * 16 + l16) * 32 + pA);
        #pragma unroll
        for (int mt = 0; mt < 2; ++mt)
            #pragma unroll
            for (int nt = 0; nt < 4; ++nt)
                acc[mt][nt] = MFMA_F16(ah[mt], bh[nt], acc[mt][nt]);
    }
}

// ---------------------------------------------------------------------------
// proj_kernel: unified q/k/v, A = Wall rows (o as M -> vectorizable q/k
// stores), B = xT rows (stacked b,n). Grid (32 n-tiles, 24 o-tiles) = 768.
// ---------------------------------------------------------------------------
__global__ __launch_bounds__(256) void proj_kernel(
    const u16* __restrict__ xT, const u16* __restrict__ Wall,
    u16* __restrict__ qT, u16* __restrict__ kT,
    u16* __restrict__ vbuf)
{
    __shared__ u16 lds[12288];
    const int lane = threadIdx.x & 63;
    const int wave = threadIdx.x >> 6;
    const int quad = lane >> 4, l16 = lane & 15;
    const int m0 = blockIdx.x * 128;      // stacked (b,n)
    const int oblk = blockIdx.y * 64;     // o in 0..1535
    const int msub = (wave & 1) * 32, nsub = (wave >> 1) * 64;

    floatx4 acc[2][4];
    #pragma unroll
    for (int i = 0; i < 2; ++i)
        #pragma unroll
        for (int j = 0; j < 4; ++j) acc[i][j] = (floatx4){0.f, 0.f, 0.f, 0.f};

    gemm_1t(Wall + (size_t)oblk * 512, xT + (size_t)m0 * 512, lds, acc, lane, wave);

    if (oblk < 1024) {
        u16* dst = (oblk < 512) ? qT : kT;
        #pragma unroll
        for (int mt = 0; mt < 2; ++mt) {
            int od = (oblk & 511) + msub + mt * 16 + quad * 4;   // head*64 + dd0
            int hsub = od >> 6, dd0 = od & 63;
            #pragma unroll
            for (int nt = 0; nt < 4; ++nt) {
                int col = m0 + nsub + nt * 16 + l16;
                int b = col >> 10, n = col & 1023;
                short4v o4;
                #pragma unroll
                for (int r = 0; r < 4; ++r) o4[r] = (short)f2h(acc[mt][nt][r]);
                *(short4v*)(dst + ((size_t)(b * 8 + hsub) * 1024 + n) * 64 + dd0) = o4;
            }
        }
    } else {
        #pragma unroll
        for (int mt = 0; mt < 2; ++mt)
            #pragma unroll
            for (int r = 0; r < 4; ++r) {
                int o = (oblk - 1024) + msub + mt * 16 + quad * 4 + r;
                #pragma unroll
                for (int nt = 0; nt < 4; ++nt) {
                    int col = m0 + nsub + nt * 16 + l16;
                    int b = col >> 10, n = col & 1023;
                    vbuf[b * 524288 + o * 1024 + n] = f2bf(acc[mt][nt][r]);
                }
            }
    }
}

// ---------------------------------------------------------------------------
// attn_kernel: 256 threads (4 waves = 64 queries), grid (head=32, qtile=16)
// = 512 blocks = 2 blocks/CU so barrier drains of one block overlap compute
// of the other. S^T formulation, P^T via register shuffles, no P LDS.
// K(f16)/V(bf16) double-buffered; LDS 32 KB.
// ---------------------------------------------------------------------------
__global__ __launch_bounds__(256) void attn_kernel(
    const u16* __restrict__ qT, const u16* __restrict__ kT,
    const u16* __restrict__ vbuf,
    u16* __restrict__ yT)
{
    __shared__ u16 lds[16384];   // 2 x 8192 shorts
    const int lane = threadIdx.x & 63;
    const int wave = threadIdx.x >> 6;      // 0..3
    const int quad = lane >> 4, l16 = lane & 15;
    const int head = blockIdx.x;
    const int i0 = blockIdx.y * 64 + wave * 16;
    const int b = head >> 3, h = head & 7;
    const u16* qp = qT + head * 65536;
    const u16* kp = kT + head * 65536;
    const u16* vb = vbuf + b * 524288 + h * 65536;
    const int srow = lane >> 2;
    const int koff = (((lane & 3) - (srow >> 1)) & 3) * 8;
    const int pA = ((quad + (l16 >> 1)) & 3) * 8;

    const int qoff = (i0 + l16) * 64 + quad * 8;
    half8 aq0 = *(const half8*)(qp + qoff);
    half8 aq1 = *(const half8*)(qp + qoff + 32);

    float lsum = 0.f;
    floatx4 oacc[4];
    #pragma unroll
    for (int dt = 0; dt < 4; ++dt) oacc[dt] = (floatx4){0.f, 0.f, 0.f, 0.f};

    const float L2E = 1.44269504f;
    const float C2  = 69.2493619f;   // 48 * log2(e)

    auto stage_kv = [&](int j0, u16* L) {
        #pragma unroll
        for (int i = 0; i < 4; ++i) {
            int c = wave + i * 4;
            const u16* s;
            if (c < 8) {
                int kc = c >> 2, r0 = (c & 3) * 16;
                s = kp + (j0 + r0 + srow) * 64 + kc * 32 + koff;
            } else {
                int c8 = c - 8, js = c8 >> 2, r0 = (c8 & 3) * 16;
                s = vb + (r0 + srow) * 1024 + j0 + js * 32 + koff;
            }
            gll16(s, L + c * 512);
        }
    };

    stage_kv(0, lds);

    const int srcA = (quad & 1) * 32 + l16;
    const int srcB = srcA + 16;
    const bool hi = (quad >> 1) != 0;

    for (int j0 = 0; j0 < 1024; j0 += 64) {
        __syncthreads();
        u16* L = lds + ((j0 >> 6) & 1) * 8192;
        if (j0 + 64 < 1024)
            stage_kv(j0 + 64, lds + (((j0 >> 6) + 1) & 1) * 8192);

        unsigned pk[4][2];
        #pragma unroll
        for (int jt = 0; jt < 4; ++jt) {
            int off = jt * 512 + l16 * 32 + pA;
            half8 kh0 = *(const half8*)(L + off);
            half8 kh1 = *(const half8*)(L + 2048 + off);
            floatx4 s = {0.f, 0.f, 0.f, 0.f};
            s = MFMA_F16(kh0, aq0, s);
            s = MFMA_F16(kh1, aq1, s);
            float p0 = __builtin_amdgcn_exp2f(s[0] * L2E - C2);
            float p1 = __builtin_amdgcn_exp2f(s[1] * L2E - C2);
            float p2 = __builtin_amdgcn_exp2f(s[2] * L2E - C2);
            float p3 = __builtin_amdgcn_exp2f(s[3] * L2E - C2);
            lsum += (p0 + p1) + (p2 + p3);
            pk[jt][0] = (unsigned)f2bf(p0) | ((unsigned)f2bf(p1) << 16);
            pk[jt][1] = (unsigned)f2bf(p2) | ((unsigned)f2bf(p3) << 16);
        }

        #pragma unroll
        for (int jc = 0; jc < 2; ++jc) {
            unsigned a0 = (unsigned)__shfl((int)pk[jc * 2][0], srcA);
            unsigned b0 = (unsigned)__shfl((int)pk[jc * 2 + 1][0], srcA);
            unsigned a1 = (unsigned)__shfl((int)pk[jc * 2][1], srcA);
            unsigned b1 = (unsigned)__shfl((int)pk[jc * 2 + 1][1], srcA);
            unsigned a2 = (unsigned)__shfl((int)pk[jc * 2][0], srcB);
            unsigned b2 = (unsigned)__shfl((int)pk[jc * 2 + 1][0], srcB);
            unsigned a3 = (unsigned)__shfl((int)pk[jc * 2][1], srcB);
            unsigned b3 = (unsigned)__shfl((int)pk[jc * 2 + 1][1], srcB);
            union { unsigned u[4]; short8 s8; } pu;
            pu.u[0] = hi ? b0 : a0;
            pu.u[1] = hi ? b1 : a1;
            pu.u[2] = hi ? b2 : a2;
            pu.u[3] = hi ? b3 : a3;
            short8 pfrag = pu.s8;
            #pragma unroll
            for (int dt = 0; dt < 4; ++dt) {
                int off = dt * 512 + l16 * 32 + pA;
                short8 vv = *(const short8*)(L + 4096 + jc * 2048 + off);
                oacc[dt] = MFMA_BF16(vv, pfrag, oacc[dt]);
            }
        }
    }

    lsum += __shfl_xor(lsum, 16);
    lsum += __shfl_xor(lsum, 32);
    const float linv = 1.0f / lsum;

    u16* yrow = yT + ((size_t)b * 1024 + i0 + l16) * 512 + h * 64;
    #pragma unroll
    for (int dt = 0; dt < 4; ++dt) {
        short4v o;
        #pragma unroll
        for (int r = 0; r < 4; ++r) o[r] = (short)f2h(oacc[dt][r] * linv);
        *(short4v*)(yrow + dt * 16 + quad * 4) = o;
    }
}

// ---------------------------------------------------------------------------
// out_kernel: Wo(f16) @ yT(f16), 64(o) x 128(b,n) tiles via gemm_1t,
// grid (32 ntiles, 8 otiles) = 256 blocks.
// ---------------------------------------------------------------------------
__global__ __launch_bounds__(256) void out_kernel(
    const u16* __restrict__ Woh, const u16* __restrict__ yT,
    void* __restrict__ out, const int* __restrict__ flag)
{
    __shared__ u16 lds[12288];
    const int isf32 = *flag;
    const int lane = threadIdx.x & 63;
    const int wave = threadIdx.x >> 6;
    const int quad = lane >> 4, l16 = lane & 15;
    const int nblk = blockIdx.x * 128;   // stacked (b,n)
    const int oblk = blockIdx.y * 64;    // o

    floatx4 acc[2][4];
    #pragma unroll
    for (int i = 0; i < 2; ++i)
        #pragma unroll
        for (int j = 0; j < 4; ++j) acc[i][j] = (floatx4){0.f, 0.f, 0.f, 0.f};

    gemm_1t(Woh + (size_t)oblk * 512, yT + (size_t)nblk * 512, lds, acc, lane, wave);

    const int msub = (wave & 1) * 32, nsub = (wave >> 1) * 64;
    #pragma unroll
    for (int mt = 0; mt < 2; ++mt)
        #pragma unroll
        for (int r = 0; r < 4; ++r) {
            int o = oblk + msub + mt * 16 + quad * 4 + r;
            #pragma unroll
            for (int nt = 0; nt < 4; ++nt) {
                int col = nblk + nsub + nt * 16 + l16;
                int b = col >> 10, n = col & 1023;
                size_t di = (size_t)b * 524288 + o * 1024 + n;
                if (isf32) ((float*)out)[di] = acc[mt][nt][r];
                else       ((u16*)out)[di] = f2bf(acc[mt][nt][r]);
            }
        }
}

extern "C" void kernel_launch(void* const* d_in, const int* in_sizes, int n_in,
                              void* d_out, int out_size, void* d_ws, size_t ws_size,
                              hipStream_t stream)
{
    const void* x  = d_in[0];
    const void* Wq = d_in[1];
    const void* Wk = d_in[2];
    const void* Wv = d_in[3];
    const void* Wo = d_in[4];

    const int NX = 4 * 512 * 1024;
    const int NW = 512 * 512;

    char* p = (char*)d_ws;
    int* flag = (int*)p; p += 64;
    u16* xT   = (u16*)p; p += (size_t)NX * 2;
    u16* Wall = (u16*)p; p += (size_t)NW * 3 * 2;
    u16* Woh  = (u16*)p; p += (size_t)NW * 2;
    u16* qT   = (u16*)p; p += (size_t)NX * 2;
    u16* kT   = (u16*)p; p += (size_t)NX * 2;
    u16* vbuf = (u16*)p; p += (size_t)NX * 2;
    u16* ybuf = (u16*)p; p += (size_t)NX * 2;

    prep_kernel<<<576, 256, 0, stream>>>(
        x, Wq, Wk, Wv, Wo, xT, Wall, Woh, flag);
    proj_kernel<<<dim3(32, 24), 256, 0, stream>>>(
        xT, Wall, qT, kT, vbuf);
    attn_kernel<<<dim3(32, 16), 256, 0, stream>>>(
        qT, kT, vbuf, ybuf);
    out_kernel<<<dim3(32, 8), 256, 0, stream>>>(
        Woh, ybuf, d_out, flag);
}